// Round 14
// baseline (1423.157 us; speedup 1.0000x reference)
//
#include <hip/hip_runtime.h>
#include <hip/hip_bf16.h>
#include <hip/hip_cooperative_groups.h>
#include <math.h>

namespace cg = cooperative_groups;

// ---- problem constants ----
constexpr int Ll = 2048, Bb = 4, DIi = 256, Hh = 4;
constexpr int TOK = Bb * Ll;       // 8192 tokens
constexpr int NC = 128;            // scan chunks per sequence
constexpr int CH = 16;             // chunk length (NC*CH = L)
constexpr float LOG2E = 1.442695040888963f;

#define DEV __device__ __forceinline__

DEV float siluf(float v)     { return v / (1.f + expf(-v)); }
DEV float softplusf(float v) { return (v > 20.f) ? v : log1pf(expf(v)); }
DEV float geluf(float v)     { return 0.5f * v * (1.f + erff(v * 0.7071067811865476f)); }

#if defined(__has_builtin)
#if __has_builtin(__builtin_amdgcn_exp2f)
#define EXP2F __builtin_amdgcn_exp2f
#endif
#endif
#ifndef EXP2F
#define EXP2F exp2f
#endif

// fp32 -> bf16 bits, round-to-nearest-even
DEV short f2bf(float f) {
    union { float f; unsigned u; } a; a.f = f;
    unsigned r = (a.u + 0x7fffu + ((a.u >> 16) & 1u)) >> 16;
    return (short)r;
}

using bf16x8 = __attribute__((ext_vector_type(8))) short;
using f16x8  = __attribute__((ext_vector_type(8))) _Float16;
using f32x4  = __attribute__((ext_vector_type(4))) float;

// ---------------- weight pre-conversion to f16 (once per launch) ----------------
__global__ __launch_bounds__(256) void wprep_kernel(
    const float* s0, const float* s1, const float* s2, const float* s3,
    const float* s4, const float* s5, const float* s6, const float* s7,
    const float* s8, const float* s9, _Float16* dst)
{
    constexpr int base[10] = {0, 16384, 409600, 802816, 827392, 851968,
                              1048576, 1146880, 1179648, 1310720};
    constexpr int nseg[10] = {16384, 393216, 393216, 24576, 24576, 196608,
                              98304, 32768, 131072, 131072};
    int seg = blockIdx.y;
    int t = blockIdx.x * 256 + threadIdx.x;
    if (t >= nseg[seg]) return;
    const float* src;
    switch (seg) {
        case 0: src = s0; break; case 1: src = s1; break;
        case 2: src = s2; break; case 3: src = s3; break;
        case 4: src = s4; break; case 5: src = s5; break;
        case 6: src = s6; break; case 7: src = s7; break;
        case 8: src = s8; break; default: src = s9; break;
    }
    dst[base[seg] + t] = (_Float16)src[t];
}

// ---------------- gather + time encoding ----------------
__global__ __launch_bounds__(256) void gather_enc_kernel(
    const int* __restrict__ ids, const int* __restrict__ tts,
    const float* __restrict__ ts, const float* __restrict__ emb,
    const float* __restrict__ temb, const float* __restrict__ freqs,
    const float* __restrict__ phases, float* __restrict__ x,
    float* __restrict__ enc)
{
    int tok = blockIdx.x * 2 + (threadIdx.x >> 7);
    int d = threadIdx.x & 127;
    float tval = ts[tok];
    int j = d & 63;
    float a = tval * freqs[j] + phases[j];
    enc[(size_t)tok * 128 + d] = (d < 64) ? sinf(a) : cosf(a);
    int id = ids[tok];
    int tt = tts[tok];
    x[(size_t)tok * 128 + d] = emb[(size_t)id * 128 + d] + temb[(size_t)tt * 128 + d];
}

// ---------------- f16 MFMA GEMM, 64x64x64 tile, 4 waves 2x2; W pre-converted f16 ----------------
// MODE 0: C[M,N] = act(A @ W^T + bias) [+ C]
// MODE 1: grid.y-1 block computes B/C projections via Bw/Cw -> bmo/cmo
// MODE 2: qkv split: cols<128 -> f32 qbuf; 128..255 -> bf16 kbf; 256..383 -> vbf^T
// LNA (Kd==128): LN fused; reads 4-float partial stats per token.
// STATS (N==128, grid.y==2): epilogue emits per-row partial (sum, sumsq).
template <int ACT, bool BIAS, bool ADD, bool LNA, int MODE, bool STATS>
__global__ __launch_bounds__(256) void gemm64_kernel(
    const float* __restrict__ A, const _Float16* __restrict__ W,
    const float* __restrict__ bias, float* __restrict__ C,
    const float* __restrict__ lnw, const float* __restrict__ lnb,
    float* __restrict__ statsbuf,
    const _Float16* __restrict__ Bw, const _Float16* __restrict__ Cw,
    float* __restrict__ bmo, float* __restrict__ cmo,
    short* __restrict__ kbf, short* __restrict__ vbf,
    int M, int N, int Kd, int lda, int ldc)
{
    __shared__ _Float16 As[64][72];
    __shared__ _Float16 Ws[64][72];
    __shared__ float sRow[STATS ? 2 : 1][STATS ? 64 : 1][2];
    const int by = blockIdx.y;
    const bool isBC = (MODE == 1) && (by == (int)gridDim.y - 1);
    const int bm0 = blockIdx.x * 64, bn0 = by * 64;
    const int tid = threadIdx.x;
    const int w = tid >> 6, l = tid & 63;
    const int wr = w >> 1, wc = w & 1;
    const int fr = l & 15, fk = (l >> 4) * 8;
    const int srow = tid >> 2, skc = (tid & 3) * 16;
    float mu = 0.f, rstd = 1.f;
    if (LNA) {
        float4 st = *(const float4*)(statsbuf + (size_t)(bm0 + srow) * 4);
        mu = (st.x + st.z) * (1.f / 128.f);
        float var = (st.y + st.w) * (1.f / 128.f) - mu * mu;
        rstd = rsqrtf(var + 1e-5f);
    }
    f32x4 acc[2][2] = {};

    for (int k0 = 0; k0 < Kd; k0 += 64) {
        const float* ap = A + (size_t)(bm0 + srow) * lda + k0 + skc;
        const _Float16* wp;
        if (isBC) {
            if (srow < 16)      wp = Bw + (size_t)srow * Kd + k0 + skc;
            else if (srow < 32) wp = Cw + (size_t)(srow - 16) * Kd + k0 + skc;
            else                wp = Bw + k0 + skc;   // dummy (masked at write)
        } else {
            wp = W + (size_t)(bn0 + srow) * Kd + k0 + skc;
        }
        float af[16];
#pragma unroll
        for (int q = 0; q < 4; q++)
            *(float4*)(af + q * 4) = *(const float4*)(ap + q * 4);
        f16x8 wb0 = *(const f16x8*)wp;
        f16x8 wb1 = *(const f16x8*)(wp + 8);
        if (LNA) {
#pragma unroll
            for (int q = 0; q < 4; q++) {
                float4 w4 = *(const float4*)(lnw + k0 + skc + q * 4);
                float4 b4 = *(const float4*)(lnb + k0 + skc + q * 4);
                af[q*4+0] = (af[q*4+0] - mu) * rstd * w4.x + b4.x;
                af[q*4+1] = (af[q*4+1] - mu) * rstd * w4.y + b4.y;
                af[q*4+2] = (af[q*4+2] - mu) * rstd * w4.z + b4.z;
                af[q*4+3] = (af[q*4+3] - mu) * rstd * w4.w + b4.w;
            }
        }
        f16x8 ab0, ab1;
#pragma unroll
        for (int q = 0; q < 8; q++) {
            ab0[q] = (_Float16)af[q]; ab1[q] = (_Float16)af[q + 8];
        }
        __syncthreads();
        *(f16x8*)&As[srow][skc]     = ab0;
        *(f16x8*)&As[srow][skc + 8] = ab1;
        *(f16x8*)&Ws[srow][skc]     = wb0;
        *(f16x8*)&Ws[srow][skc + 8] = wb1;
        __syncthreads();
#pragma unroll
        for (int ks = 0; ks < 64; ks += 32) {
            f16x8 afr0 = *(const f16x8*)&As[wr * 32 + fr][ks + fk];
            f16x8 afr1 = *(const f16x8*)&As[wr * 32 + 16 + fr][ks + fk];
            f16x8 wfr0 = *(const f16x8*)&Ws[wc * 32 + fr][ks + fk];
            f16x8 wfr1 = *(const f16x8*)&Ws[wc * 32 + 16 + fr][ks + fk];
            acc[0][0] = __builtin_amdgcn_mfma_f32_16x16x32_f16(afr0, wfr0, acc[0][0], 0, 0, 0);
            acc[0][1] = __builtin_amdgcn_mfma_f32_16x16x32_f16(afr0, wfr1, acc[0][1], 0, 0, 0);
            acc[1][0] = __builtin_amdgcn_mfma_f32_16x16x32_f16(afr1, wfr0, acc[1][0], 0, 0, 0);
            acc[1][1] = __builtin_amdgcn_mfma_f32_16x16x32_f16(afr1, wfr1, acc[1][1], 0, 0, 0);
        }
    }
    float rs_[2][4], rq_[2][4];
    if (STATS) {
#pragma unroll
        for (int ri = 0; ri < 2; ri++)
#pragma unroll
            for (int r = 0; r < 4; r++) { rs_[ri][r] = 0.f; rq_[ri][r] = 0.f; }
    }
#pragma unroll
    for (int ri = 0; ri < 2; ri++)
#pragma unroll
    for (int ci = 0; ci < 2; ci++) {
        const int lcol = wc * 32 + ci * 16 + fr;
        const int col = bn0 + lcol;
        const int row0 = bm0 + wr * 32 + ri * 16 + (l >> 4) * 4;
        if (isBC) {
            if (lcol < 32) {
                float* dst = (lcol < 16) ? bmo : cmo;
                const int cc = lcol & 15;
#pragma unroll
                for (int r = 0; r < 4; r++)
                    dst[(size_t)(row0 + r) * 16 + cc] = acc[ri][ci][r];
            }
        } else if (MODE == 2) {
            const float bv = bias[col];
            const int b = row0 >> 11, tl0 = row0 & 2047;
            if (col < 128) {
#pragma unroll
                for (int r = 0; r < 4; r++)
                    C[(size_t)(row0 + r) * 128 + col] = acc[ri][ci][r] + bv;
            } else if (col < 256) {
                const int hc = col - 128;
                short* kp = kbf + ((size_t)(b * 4 + (hc >> 5)) * 2048 + tl0) * 32 + (hc & 31);
#pragma unroll
                for (int r = 0; r < 4; r++)
                    kp[(size_t)r * 32] = f2bf(acc[ri][ci][r] + bv);
            } else {
                const int hc = col - 256;
                short4 vk;
#pragma unroll
                for (int r = 0; r < 4; r++)
                    ((short*)&vk)[r] = f2bf(acc[ri][ci][r] + bv);
                *(short4*)(vbf + ((size_t)(b * 4 + (hc >> 5)) * 32 + (hc & 31)) * 2048 + tl0) = vk;
            }
        } else {
            const float bv = BIAS ? bias[col] : 0.f;
#pragma unroll
            for (int r = 0; r < 4; r++) {
                float t = acc[ri][ci][r] + bv;
                if (ACT == 1) t = softplusf(t);
                if (ACT == 2) t = geluf(t);
                float* p = C + (size_t)(row0 + r) * ldc + col;
                if (ADD) t += *p;
                *p = t;
                if (STATS) { rs_[ri][r] += t; rq_[ri][r] += t * t; }
            }
        }
    }
    if (STATS) {
        const int g = l >> 4;
#pragma unroll
        for (int ri = 0; ri < 2; ri++)
#pragma unroll
        for (int r = 0; r < 4; r++) {
            float v = rs_[ri][r], q = rq_[ri][r];
            v += __shfl_xor(v, 1); q += __shfl_xor(q, 1);
            v += __shfl_xor(v, 2); q += __shfl_xor(q, 2);
            v += __shfl_xor(v, 4); q += __shfl_xor(q, 4);
            v += __shfl_xor(v, 8); q += __shfl_xor(q, 8);
            if (fr == 0) {
                int rowl = wr * 32 + ri * 16 + g * 4 + r;
                sRow[wc][rowl][0] = v;
                sRow[wc][rowl][1] = q;
            }
        }
        __syncthreads();
        if (tid < 128) {
            int row = tid >> 1, j = tid & 1;
            statsbuf[(size_t)(bm0 + row) * 4 + by * 2 + j] =
                sRow[0][row][j] + sRow[1][row][j];
        }
    }
}

// ---------------- causal depthwise conv (K=4) + silu, 4 channels/thread ----------------
__global__ __launch_bounds__(256) void conv_kernel(
    const float* __restrict__ xz, const float* __restrict__ cw,
    const float* __restrict__ cb, float* __restrict__ xc)
{
    int g = blockIdx.x * 256 + threadIdx.x;     // TOK * 64 threads
    int c4 = g & 63;
    int t  = (g >> 6) & 2047;
    int b  = g >> 17;
    int c  = c4 * 4;
    float4 w0 = *(const float4*)(cw + (size_t)c * 4);
    float4 w1 = *(const float4*)(cw + (size_t)(c + 1) * 4);
    float4 w2 = *(const float4*)(cw + (size_t)(c + 2) * 4);
    float4 w3 = *(const float4*)(cw + (size_t)(c + 3) * 4);
    float4 bi = *(const float4*)(cb + c);
    float4 xk[4];
#pragma unroll
    for (int kk = 0; kk < 4; kk++) {
        int tt = t - 3 + kk;
        if (tt >= 0) xk[kk] = *(const float4*)(xz + ((size_t)b * 2048 + tt) * 512 + c);
        else xk[kk] = make_float4(0.f, 0.f, 0.f, 0.f);
    }
    float4 r;
    r.x = bi.x + xk[0].x * w0.x + xk[1].x * w0.y + xk[2].x * w0.z + xk[3].x * w0.w;
    r.y = bi.y + xk[0].y * w1.x + xk[1].y * w1.y + xk[2].y * w1.z + xk[3].y * w1.w;
    r.z = bi.z + xk[0].z * w2.x + xk[1].z * w2.y + xk[2].z * w2.z + xk[3].z * w2.w;
    r.w = bi.w + xk[0].w * w3.x + xk[1].w * w3.y + xk[2].w * w3.z + xk[3].w * w3.w;
    r.x = siluf(r.x); r.y = siluf(r.y); r.z = siluf(r.z); r.w = siluf(r.w);
    *(float4*)(xc + ((size_t)b * 2048 + t) * 256 + c) = r;
}

// ---------------- fused 3-phase scan (cooperative launch, grid = Bb*NC blocks) ----------------
// phase1: per-chunk local state -> F, sumdt
// phase2: sequential chunk prefix IN-PLACE on F (first 64 blocks)
// phase3: replay with true h0, emit gated y
// sB/sC/A2 loaded once and persist across phases (blocks are co-resident).
__global__ __launch_bounds__(256) void scan_fused_kernel(
    const float* __restrict__ dt, const float* __restrict__ xc,
    const float* __restrict__ bm, const float* __restrict__ cm,
    const float* __restrict__ xz, const float* __restrict__ Alog,
    const float* __restrict__ Dp, float* __restrict__ F,
    float* __restrict__ sumdt, float* __restrict__ y)
{
    cg::grid_group grid = cg::this_grid();
    const int c = threadIdx.x;
    const int k = blockIdx.x & (NC - 1);
    const int b = blockIdx.x / NC;
    __shared__ float sB[CH][16], sC[CH][16];
    const int t0 = k * CH;
    if (threadIdx.x < CH * 4) {
        int r = threadIdx.x >> 2, c4 = (threadIdx.x & 3) << 2;
        *(float4*)&sB[r][c4] = *(const float4*)(bm + ((size_t)b * 2048 + t0 + r) * 16 + c4);
        *(float4*)&sC[r][c4] = *(const float4*)(cm + ((size_t)b * 2048 + t0 + r) * 16 + c4);
    }
    float A2[16];
#pragma unroll
    for (int s = 0; s < 16; s++) A2[s] = -expf(Alog[(size_t)c * 16 + s]) * LOG2E;
    __syncthreads();

    // ---- phase 1 ----
    float h[16] = {};
    float sd = 0.f;
    const size_t base = ((size_t)b * 2048 + t0) * 256 + c;
    for (int tt = 0; tt < CH; tt++) {
        float d  = dt[base + (size_t)tt * 256];
        float xv = xc[base + (size_t)tt * 256];
        sd += d;
        float xdt = xv * d;
#pragma unroll
        for (int s = 0; s < 16; s++) h[s] = h[s] * EXP2F(A2[s] * d) + xdt * sB[tt][s];
    }
    const size_t fo = (((size_t)b * NC + k) * 256 + c) * 16;
#pragma unroll
    for (int s = 0; s < 16; s += 4) *(float4*)(F + fo + s) = make_float4(h[s], h[s+1], h[s+2], h[s+3]);
    sumdt[((size_t)b * NC + k) * 256 + c] = sd;

    grid.sync();

    // ---- phase 2 (first 64 blocks = 16384 threads) ----
    if (blockIdx.x < 64) {
        int g = blockIdx.x * 256 + threadIdx.x;
        int s2 = g & 15, c2 = (g >> 4) & 255, b2 = g >> 12;
        float A2p = -expf(Alog[(size_t)c2 * 16 + s2]) * LOG2E;
        float hp = 0.f;
        for (int kk = 0; kk < NC; kk++) {
            size_t o = (((size_t)b2 * NC + kk) * 256 + c2) * 16 + s2;
            float tmp = F[o];
            F[o] = hp;
            hp = hp * EXP2F(A2p * sumdt[((size_t)b2 * NC + kk) * 256 + c2]) + tmp;
        }
    }

    grid.sync();

    // ---- phase 3 ----
#pragma unroll
    for (int s = 0; s < 16; s++) h[s] = F[fo + s];
    float Dv = Dp[c];
    const size_t zbase = ((size_t)b * 2048 + t0) * 512 + 256 + c;
    for (int tt = 0; tt < CH; tt++) {
        float d  = dt[base + (size_t)tt * 256];
        float xv = xc[base + (size_t)tt * 256];
        float xdt = xv * d;
        float yv = 0.f;
#pragma unroll
        for (int s = 0; s < 16; s++) {
            h[s] = h[s] * EXP2F(A2[s] * d) + xdt * sB[tt][s];
            yv += h[s] * sC[tt][s];
        }
        yv += xv * Dv;
        float zv = xz[zbase + (size_t)tt * 512];
        y[base + (size_t)tt * 256] = yv * siluf(zv);
    }
}

// ---------------- bf16 MFMA flash attention, split-K x4, LDS-staged K/V ----------------
__global__ __launch_bounds__(256) void attn_part_kernel(
    const float* __restrict__ qbuf, const short* __restrict__ kbf,
    const short* __restrict__ vbf, float* __restrict__ pO, float* __restrict__ pml)
{
    __shared__ short Klds[2][64 * 32];
    __shared__ short Vlds[2][32 * 64];
    __shared__ short Pt[4][64][18];
    const int qt = blockIdx.x, b = blockIdx.z;
    const int h = blockIdx.y >> 2, sp = blockIdx.y & 3;
    const int tid = threadIdx.x;
    const int w = tid >> 6, l = tid & 63;
    const int q16 = l & 15, g = l >> 4;
    const float cQ = 0.25503634043f;      // log2(e)/sqrt(32)

    const int qrow = qt * 64 + w * 16 + q16;
    const float* qp = qbuf + ((size_t)(b * 2048 + qrow)) * 128 + 32 * h + g * 8;
    bf16x8 qfrag;
    {
        float qf[8];
        *(float4*)qf       = *(const float4*)qp;
        *(float4*)(qf + 4) = *(const float4*)(qp + 4);
#pragma unroll
        for (int i = 0; i < 8; i++) qfrag[i] = f2bf(qf[i] * cQ);
    }
    const int bh = b * 4 + h;
    const short* kb = kbf + ((size_t)bh * 2048) * 32;   // [k][d]
    const short* vb = vbf + ((size_t)bh * 32) * 2048;   // [d][k]

    const int vrow = tid >> 3;
    const int vsw  = ((tid & 7) * 16) ^ ((vrow & 7) << 4);
    const int ts0 = sp * 8;

    bf16x8 kst, vst;
    auto ldregs = [&](int t) {
        kst = *(const bf16x8*)(kb + (size_t)t * 2048 + tid * 8);
        vst = *(const bf16x8*)(vb + (size_t)vrow * 2048 + t * 64 + (vsw >> 1));
    };
    auto dswrite = [&](int buf) {
        *(bf16x8*)&Klds[buf][tid * 8] = kst;
        *(bf16x8*)&Vlds[buf][tid * 8] = vst;
    };

    float m = -1e30f, lsum = 0.f;
    f32x4 O0 = {0.f, 0.f, 0.f, 0.f}, O1 = {0.f, 0.f, 0.f, 0.f};
    const f32x4 zf = {0.f, 0.f, 0.f, 0.f};

    auto step = [&](int buf) {
        bf16x8 kf[4];
#pragma unroll
        for (int kt = 0; kt < 4; kt++)
            kf[kt] = *(const bf16x8*)&Klds[buf][(kt * 16 + q16) * 32 + g * 8];
        f32x4 St[4];
#pragma unroll
        for (int kt = 0; kt < 4; kt++)
            St[kt] = __builtin_amdgcn_mfma_f32_16x16x32_bf16(kf[kt], qfrag, zf, 0, 0, 0);
        float pm = St[0][0];
#pragma unroll
        for (int kt = 0; kt < 4; kt++)
#pragma unroll
            for (int r = 0; r < 4; r++) pm = fmaxf(pm, St[kt][r]);
        pm = fmaxf(pm, __shfl_xor(pm, 16));
        pm = fmaxf(pm, __shfl_xor(pm, 32));
        float mn = fmaxf(m, pm);
        float rs = EXP2F(m - mn);
        float ps = 0.f;
#pragma unroll
        for (int kt = 0; kt < 4; kt++)
#pragma unroll
            for (int r = 0; r < 4; r++) {
                float p = EXP2F(St[kt][r] - mn);
                ps += p;
                Pt[w][kt * 16 + g * 4 + r][q16] = f2bf(p);
            }
        ps += __shfl_xor(ps, 16);
        ps += __shfl_xor(ps, 32);
        lsum = lsum * rs + ps;
        m = mn;
        O0 *= rs; O1 *= rs;
#pragma unroll
        for (int c = 0; c < 2; c++) {
            bf16x8 pb;
#pragma unroll
            for (int i = 0; i < 8; i++) pb[i] = Pt[w][c * 32 + g * 8 + i][q16];
#pragma unroll
            for (int hf = 0; hf < 2; hf++) {
                const int d = q16 + 16 * hf;
                bf16x8 vf = *(const bf16x8*)&Vlds[buf][d * 64 + ((c * 32 + g * 8) ^ ((d & 7) << 3))];
                if (hf == 0) O0 = __builtin_amdgcn_mfma_f32_16x16x32_bf16(vf, pb, O0, 0, 0, 0);
                else         O1 = __builtin_amdgcn_mfma_f32_16x16x32_bf16(vf, pb, O1, 0, 0, 0);
            }
        }
    };

    ldregs(ts0);
    dswrite(0);
    ldregs(ts0 + 1);
    int cur = 0;
    for (int i = 0; i < 8; i++) {
        __syncthreads();
        if (i + 1 < 8) {
            dswrite(cur ^ 1);
            if (i + 2 < 8) ldregs(ts0 + i + 2);
        }
        step(cur);
        cur ^= 1;
    }

    size_t po = (((size_t)(bh * 4 + sp)) * 2048 + qrow) * 32;
#pragma unroll
    for (int r = 0; r < 4; r++) {
        pO[po + g * 4 + r]      = O0[r];
        pO[po + 16 + g * 4 + r] = O1[r];
    }
    if (g == 0) {
        size_t mo = (((size_t)(bh * 4 + sp)) * 2048 + qrow) * 2;
        pml[mo]     = m;
        pml[mo + 1] = lsum;
    }
}

// ---------------- attention combine: merge 4 split-K partials ----------------
__global__ __launch_bounds__(256) void attn_comb_kernel(
    const float* __restrict__ pO, const float* __restrict__ pml,
    float* __restrict__ aout)
{
    int gid = blockIdx.x * 256 + threadIdx.x;   // bh(4b) q(11b) d(5b)
    int d = gid & 31, q = (gid >> 5) & 2047, bh = gid >> 16;
    float m[4], lv[4], M = -1e30f;
#pragma unroll
    for (int s = 0; s < 4; s++) {
        size_t mo = (((size_t)(bh * 4 + s)) * 2048 + q) * 2;
        m[s] = pml[mo]; lv[s] = pml[mo + 1];
        M = fmaxf(M, m[s]);
    }
    float L = 0.f, o = 0.f;
#pragma unroll
    for (int s = 0; s < 4; s++) {
        float wgt = EXP2F(m[s] - M);
        L += lv[s] * wgt;
        o += pO[(((size_t)(bh * 4 + s)) * 2048 + q) * 32 + d] * wgt;
    }
    int b = bh >> 2, h = bh & 3;
    aout[((size_t)(b * 2048 + q)) * 128 + h * 32 + d] = o / L;
}

// ---------------- head ----------------
__global__ __launch_bounds__(128) void head_kernel(
    const float* __restrict__ x, const float* __restrict__ w,
    const float* __restrict__ bsp, const float* __restrict__ hw,
    const float* __restrict__ hb, float* __restrict__ out)
{
    int bb = blockIdx.x;
    int d = threadIdx.x;
    int wid = d >> 6, lane = d & 63;
    float v = x[(size_t)bb * 2048 * 128 + d];
    float s = v, sq = v * v;
#pragma unroll
    for (int o = 32; o > 0; o >>= 1) { s += __shfl_xor(s, o); sq += __shfl_xor(sq, o); }
    __shared__ float red[4];
    if (lane == 0) { red[wid] = s; red[2 + wid] = sq; }
    __syncthreads();
    s = red[0] + red[1]; sq = red[2] + red[3];
    float mu = s * (1.f / 128.f);
    float var = sq * (1.f / 128.f) - mu * mu;
    float xn = (v - mu) * rsqrtf(var + 1e-5f) * w[d] + bsp[d];
    float pr = xn * hw[d];
#pragma unroll
    for (int o = 32; o > 0; o >>= 1) pr += __shfl_xor(pr, o);
    __syncthreads();
    if (lane == 0) red[wid] = pr;
    __syncthreads();
    if (d == 0) out[bb] = red[0] + red[1] + hb[0];
}

// ---------------- workspace layout (floats) ----------------
constexpr size_t OFF_X  = 0;                          // x: 1M
constexpr size_t OFF_XZ = (size_t)1 << 20;            // xz / ff / attn pO: 4M
constexpr size_t OFF_XC = (size_t)5 << 20;            // xc (mamba) / qbuf (attn): 2M
constexpr size_t OFF_DT = (size_t)7 << 20;            // dt / attn pml: 2M
constexpr size_t OFF_Y  = (size_t)9 << 20;            // y / attn out: 2M
constexpr size_t OFF_BM = (size_t)11 << 20;           // 128K
constexpr size_t OFF_CM = OFF_BM + 131072;            // 128K
constexpr size_t OFF_SD = OFF_CM + 131072;            // 128K
constexpr size_t OFF_ST = OFF_SD + 131072;            // 32K (TOK x 4 partial stats)
constexpr size_t OFF_F  = OFF_ST + 32768;             // 2M: scan F / attn kbf+vbf / embed enc
constexpr size_t OFF_WF = OFF_F + ((size_t)2 << 20);  // 720896 floats of f16 weights
constexpr size_t WS_FLOATS = OFF_WF + 720896;

extern "C" void kernel_launch(void* const* d_in, const int* in_sizes, int n_in,
                              void* d_out, int out_size, void* d_ws, size_t ws_size,
                              hipStream_t stream)
{
    const int*   ids   = (const int*)d_in[0];
    const int*   tts   = (const int*)d_in[1];
    const float* tstmp = (const float*)d_in[2];
    const float* emb   = (const float*)d_in[3];
    const float* temb  = (const float*)d_in[4];
    const float* tef   = (const float*)d_in[5];
    const float* tep   = (const float*)d_in[6];
    const float* tew   = (const float*)d_in[7];
    const float* tebi  = (const float*)d_in[8];
    const float* mnw   = (const float*)d_in[9];
    const float* mnb   = (const float*)d_in[10];
    const float* minw  = (const float*)d_in[11];
    const float* mcwp  = (const float*)d_in[12];
    const float* mcb   = (const float*)d_in[13];
    const float* mdtw  = (const float*)d_in[14];
    const float* mdtb  = (const float*)d_in[15];
    const float* mbw   = (const float*)d_in[16];
    const float* mcw2  = (const float*)d_in[17];
    const float* mD    = (const float*)d_in[18];
    const float* mAl   = (const float*)d_in[19];
    const float* mow   = (const float*)d_in[20];
    const float* al1w  = (const float*)d_in[21];
    const float* al1b  = (const float*)d_in[22];
    const float* aqkvw = (const float*)d_in[23];
    const float* aqkvb = (const float*)d_in[24];
    const float* aow   = (const float*)d_in[25];
    const float* aob   = (const float*)d_in[26];
    const float* al2w  = (const float*)d_in[27];
    const float* al2b  = (const float*)d_in[28];
    const float* af1w  = (const float*)d_in[29];
    const float* af1b  = (const float*)d_in[30];
    const float* af2w  = (const float*)d_in[31];
    const float* af2b  = (const float*)d_in[32];
    const float* hlnw  = (const float*)d_in[33];
    const float* hlnb  = (const float*)d_in[34];
    const float* hw    = (const float*)d_in[35];
    const float* hb    = (const float*)d_in[36];
    float* out = (float*)d_out;
    float* wsf = (float*)d_ws;
    if (ws_size < WS_FLOATS * sizeof(float)) return;

    float* x    = wsf + OFF_X;
    float* xz   = wsf + OFF_XZ;
    float* xc   = wsf + OFF_XC;
    float* dtb  = wsf + OFF_DT;
    float* yb   = wsf + OFF_Y;
    float* bm   = wsf + OFF_BM;
    float* cm   = wsf + OFF_CM;
    float* sdb  = wsf + OFF_SD;
    float* stats4 = wsf + OFF_ST;                  // [TOK][4] partial LN stats
    float* Fb   = wsf + OFF_F;
    float* ff   = xz;
    float* aout = yb;
    float* qbuf = xc;                              // attn-time only
    float* pO   = xz;                              // attn-time only
    float* pml  = dtb;                             // attn-time only
    float* encb = Fb;                              // embed-time only
    short* kbf  = (short*)(wsf + OFF_F);           // attn-time only
    short* vbf  = (short*)(wsf + OFF_F + ((size_t)1 << 20));
    _Float16* wf16 = (_Float16*)(wsf + OFF_WF);

    const _Float16* tew16   = wf16;
    const _Float16* minw16  = wf16 + 16384;
    const _Float16* mdtw16  = wf16 + 409600;
    const _Float16* mbw16   = wf16 + 802816;
    const _Float16* mcw216  = wf16 + 827392;
    const _Float16* mow16   = wf16 + 851968;
    const _Float16* aqkvw16 = wf16 + 1048576;
    const _Float16* aow16   = wf16 + 1146880;
    const _Float16* af1w16  = wf16 + 1179648;
    const _Float16* af2w16  = wf16 + 1310720;

    wprep_kernel<<<dim3(1536, 10), 256, 0, stream>>>(
        tew, minw, mdtw, mbw, mcw2, mow, aqkvw, aow, af1w, af2w, wf16);

    gather_enc_kernel<<<TOK / 2, 256, 0, stream>>>(ids, tts, tstmp, emb, temb, tef, tep, x, encb);
    // embed GEMM produces x AND its LN partial stats
    gemm64_kernel<0, true, true, false, 0, true><<<dim3(128, 2), 256, 0, stream>>>(
        encb, tew16, tebi, x, nullptr, nullptr, stats4, nullptr, nullptr,
        nullptr, nullptr, nullptr, nullptr, TOK, 128, 128, 128, 128);

    int mi = 0, ai = 0;
    for (int i = 0; i < 8; i++) {
        if ((i + 1) % 4 == 0) {
            // -------- attention layer --------
            gemm64_kernel<0, true, false, true, 2, false><<<dim3(128, 6), 256, 0, stream>>>(
                x, aqkvw16 + (size_t)ai * 49152, aqkvb + ai * 384, qbuf,
                al1w + ai * 128, al1b + ai * 128, stats4, nullptr, nullptr,
                nullptr, nullptr, kbf, vbf, TOK, 384, 128, 128, 128);
            attn_part_kernel<<<dim3(32, 16, Bb), 256, 0, stream>>>(qbuf, kbf, vbf, pO, pml);
            attn_comb_kernel<<<4096, 256, 0, stream>>>(pO, pml, aout);
            gemm64_kernel<0, true, true, false, 0, true><<<dim3(128, 2), 256, 0, stream>>>(
                aout, aow16 + (size_t)ai * 16384, aob + ai * 128, x,
                nullptr, nullptr, stats4, nullptr, nullptr,
                nullptr, nullptr, nullptr, nullptr, TOK, 128, 128, 128, 128);
            gemm64_kernel<2, true, false, true, 0, false><<<dim3(128, 8), 256, 0, stream>>>(
                x, af1w16 + (size_t)ai * 65536, af1b + ai * 512, ff,
                al2w + ai * 128, al2b + ai * 128, stats4, nullptr, nullptr,
                nullptr, nullptr, nullptr, nullptr, TOK, 512, 128, 128, 512);
            gemm64_kernel<0, true, true, false, 0, true><<<dim3(128, 2), 256, 0, stream>>>(
                ff, af2w16 + (size_t)ai * 65536, af2b + ai * 128, x,
                nullptr, nullptr, stats4, nullptr, nullptr,
                nullptr, nullptr, nullptr, nullptr, TOK, 128, 512, 512, 128);
            ai++;
        } else {
            // -------- mamba layer --------
            const float* Al = mAl + (size_t)mi * DIi * 16;
            const float* Dpv = mD + (size_t)mi * 256;
            gemm64_kernel<0, false, false, true, 0, false><<<dim3(128, 8), 256, 0, stream>>>(
                x, minw16 + (size_t)mi * 65536, nullptr, xz,
                mnw + mi * 128, mnb + mi * 128, stats4, nullptr, nullptr,
                nullptr, nullptr, nullptr, nullptr, TOK, 512, 128, 128, 512);
            conv_kernel<<<2048, 256, 0, stream>>>(xz, mcwp + (size_t)mi * DIi * 4, mcb + mi * DIi, xc);
            gemm64_kernel<1, true, false, false, 1, false><<<dim3(128, 5), 256, 0, stream>>>(
                xc, mdtw16 + (size_t)mi * 65536, mdtb + mi * 256, dtb,
                nullptr, nullptr, nullptr,
                mbw16 + (size_t)mi * 4096, mcw216 + (size_t)mi * 4096,
                bm, cm, nullptr, nullptr, TOK, 256, 256, 256, 256);
            {
                void* scanArgs[10] = {
                    (void*)&dtb, (void*)&xc, (void*)&bm, (void*)&cm, (void*)&xz,
                    (void*)&Al, (void*)&Dpv, (void*)&Fb, (void*)&sdb, (void*)&yb };
                hipLaunchCooperativeKernel((const void*)scan_fused_kernel,
                                           dim3(Bb * NC), dim3(256), scanArgs, 0, stream);
            }
            gemm64_kernel<0, false, true, false, 0, true><<<dim3(128, 2), 256, 0, stream>>>(
                yb, mow16 + (size_t)mi * 32768, nullptr, x,
                nullptr, nullptr, stats4, nullptr, nullptr,
                nullptr, nullptr, nullptr, nullptr, TOK, 128, 256, 256, 128);
            mi++;
        }
    }
    head_kernel<<<Bb, 128, 0, stream>>>(x, hlnw, hlnb, hw, hb, out);
}

// Round 15
// 660.869 us; speedup vs baseline: 2.1535x; 2.1535x over previous
//
#include <hip/hip_runtime.h>
#include <hip/hip_bf16.h>
#include <math.h>

// ---- problem constants ----
constexpr int Ll = 2048, Bb = 4, DIi = 256, Hh = 4;
constexpr int TOK = Bb * Ll;       // 8192 tokens
constexpr int NC = 128;            // scan chunks per sequence
constexpr int CH = 16;             // chunk length (NC*CH = L)
constexpr float LOG2E = 1.442695040888963f;

#define DEV __device__ __forceinline__

DEV float siluf(float v)     { return v / (1.f + expf(-v)); }
DEV float softplusf(float v) { return (v > 20.f) ? v : log1pf(expf(v)); }
DEV float geluf(float v)     { return 0.5f * v * (1.f + erff(v * 0.7071067811865476f)); }

#if defined(__has_builtin)
#if __has_builtin(__builtin_amdgcn_exp2f)
#define EXP2F __builtin_amdgcn_exp2f
#endif
#endif
#ifndef EXP2F
#define EXP2F exp2f
#endif

// fp32 -> bf16 bits, round-to-nearest-even
DEV short f2bf(float f) {
    union { float f; unsigned u; } a; a.f = f;
    unsigned r = (a.u + 0x7fffu + ((a.u >> 16) & 1u)) >> 16;
    return (short)r;
}

using bf16x8 = __attribute__((ext_vector_type(8))) short;
using f16x8  = __attribute__((ext_vector_type(8))) _Float16;
using f32x4  = __attribute__((ext_vector_type(4))) float;

// ---------------- weight pre-conversion to f16 (once per launch) ----------------
__global__ __launch_bounds__(256) void wprep_kernel(
    const float* s0, const float* s1, const float* s2, const float* s3,
    const float* s4, const float* s5, const float* s6, const float* s7,
    const float* s8, const float* s9, _Float16* dst)
{
    constexpr int base[10] = {0, 16384, 409600, 802816, 827392, 851968,
                              1048576, 1146880, 1179648, 1310720};
    constexpr int nseg[10] = {16384, 393216, 393216, 24576, 24576, 196608,
                              98304, 32768, 131072, 131072};
    int seg = blockIdx.y;
    int t = blockIdx.x * 256 + threadIdx.x;
    if (t >= nseg[seg]) return;
    const float* src;
    switch (seg) {
        case 0: src = s0; break; case 1: src = s1; break;
        case 2: src = s2; break; case 3: src = s3; break;
        case 4: src = s4; break; case 5: src = s5; break;
        case 6: src = s6; break; case 7: src = s7; break;
        case 8: src = s8; break; default: src = s9; break;
    }
    dst[base[seg] + t] = (_Float16)src[t];
}

// ---------------- gather + time encoding ----------------
__global__ __launch_bounds__(256) void gather_enc_kernel(
    const int* __restrict__ ids, const int* __restrict__ tts,
    const float* __restrict__ ts, const float* __restrict__ emb,
    const float* __restrict__ temb, const float* __restrict__ freqs,
    const float* __restrict__ phases, float* __restrict__ x,
    float* __restrict__ enc)
{
    int tok = blockIdx.x * 2 + (threadIdx.x >> 7);
    int d = threadIdx.x & 127;
    float tval = ts[tok];
    int j = d & 63;
    float a = tval * freqs[j] + phases[j];
    enc[(size_t)tok * 128 + d] = (d < 64) ? sinf(a) : cosf(a);
    int id = ids[tok];
    int tt = tts[tok];
    x[(size_t)tok * 128 + d] = emb[(size_t)id * 128 + d] + temb[(size_t)tt * 128 + d];
}

// ---------------- f16 MFMA GEMM, 64x64x64 tile, 4 waves 2x2; W pre-converted f16 ----------------
// MODE 0: C[M,N] = act(A @ W^T + bias) [+ C]
// MODE 1: grid.y-1 block computes B/C projections via Bw/Cw -> bmo/cmo
// MODE 2: qkv split: cols<128 -> f32 qbuf; 128..255 -> bf16 kbf; 256..383 -> vbf^T
// LNA (Kd==128): LN fused; reads 4-float partial stats (sum0,sq0,sum1,sq1) per token.
// STATS (N==128, grid.y==2): epilogue emits per-row partial (sum, sumsq) over this
//   block's 64 cols into statsbuf[tok*4 + by*2 + {0,1}] — producer-side LN stats.
template <int ACT, bool BIAS, bool ADD, bool LNA, int MODE, bool STATS>
__global__ __launch_bounds__(256) void gemm64_kernel(
    const float* __restrict__ A, const _Float16* __restrict__ W,
    const float* __restrict__ bias, float* __restrict__ C,
    const float* __restrict__ lnw, const float* __restrict__ lnb,
    float* __restrict__ statsbuf,
    const _Float16* __restrict__ Bw, const _Float16* __restrict__ Cw,
    float* __restrict__ bmo, float* __restrict__ cmo,
    short* __restrict__ kbf, short* __restrict__ vbf,
    int M, int N, int Kd, int lda, int ldc)
{
    __shared__ _Float16 As[64][72];
    __shared__ _Float16 Ws[64][72];
    __shared__ float sRow[STATS ? 2 : 1][STATS ? 64 : 1][2];
    const int by = blockIdx.y;
    const bool isBC = (MODE == 1) && (by == (int)gridDim.y - 1);
    const int bm0 = blockIdx.x * 64, bn0 = by * 64;
    const int tid = threadIdx.x;
    const int w = tid >> 6, l = tid & 63;
    const int wr = w >> 1, wc = w & 1;
    const int fr = l & 15, fk = (l >> 4) * 8;
    const int srow = tid >> 2, skc = (tid & 3) * 16;
    float mu = 0.f, rstd = 1.f;
    if (LNA) {
        float4 st = *(const float4*)(statsbuf + (size_t)(bm0 + srow) * 4);
        mu = (st.x + st.z) * (1.f / 128.f);
        float var = (st.y + st.w) * (1.f / 128.f) - mu * mu;
        rstd = rsqrtf(var + 1e-5f);
    }
    f32x4 acc[2][2] = {};

    for (int k0 = 0; k0 < Kd; k0 += 64) {
        const float* ap = A + (size_t)(bm0 + srow) * lda + k0 + skc;
        const _Float16* wp;
        if (isBC) {
            if (srow < 16)      wp = Bw + (size_t)srow * Kd + k0 + skc;
            else if (srow < 32) wp = Cw + (size_t)(srow - 16) * Kd + k0 + skc;
            else                wp = Bw + k0 + skc;   // dummy (masked at write)
        } else {
            wp = W + (size_t)(bn0 + srow) * Kd + k0 + skc;
        }
        float af[16];
#pragma unroll
        for (int q = 0; q < 4; q++)
            *(float4*)(af + q * 4) = *(const float4*)(ap + q * 4);
        f16x8 wb0 = *(const f16x8*)wp;
        f16x8 wb1 = *(const f16x8*)(wp + 8);
        if (LNA) {
#pragma unroll
            for (int q = 0; q < 4; q++) {
                float4 w4 = *(const float4*)(lnw + k0 + skc + q * 4);
                float4 b4 = *(const float4*)(lnb + k0 + skc + q * 4);
                af[q*4+0] = (af[q*4+0] - mu) * rstd * w4.x + b4.x;
                af[q*4+1] = (af[q*4+1] - mu) * rstd * w4.y + b4.y;
                af[q*4+2] = (af[q*4+2] - mu) * rstd * w4.z + b4.z;
                af[q*4+3] = (af[q*4+3] - mu) * rstd * w4.w + b4.w;
            }
        }
        f16x8 ab0, ab1;
#pragma unroll
        for (int q = 0; q < 8; q++) {
            ab0[q] = (_Float16)af[q]; ab1[q] = (_Float16)af[q + 8];
        }
        __syncthreads();
        *(f16x8*)&As[srow][skc]     = ab0;
        *(f16x8*)&As[srow][skc + 8] = ab1;
        *(f16x8*)&Ws[srow][skc]     = wb0;
        *(f16x8*)&Ws[srow][skc + 8] = wb1;
        __syncthreads();
#pragma unroll
        for (int ks = 0; ks < 64; ks += 32) {
            f16x8 afr0 = *(const f16x8*)&As[wr * 32 + fr][ks + fk];
            f16x8 afr1 = *(const f16x8*)&As[wr * 32 + 16 + fr][ks + fk];
            f16x8 wfr0 = *(const f16x8*)&Ws[wc * 32 + fr][ks + fk];
            f16x8 wfr1 = *(const f16x8*)&Ws[wc * 32 + 16 + fr][ks + fk];
            acc[0][0] = __builtin_amdgcn_mfma_f32_16x16x32_f16(afr0, wfr0, acc[0][0], 0, 0, 0);
            acc[0][1] = __builtin_amdgcn_mfma_f32_16x16x32_f16(afr0, wfr1, acc[0][1], 0, 0, 0);
            acc[1][0] = __builtin_amdgcn_mfma_f32_16x16x32_f16(afr1, wfr0, acc[1][0], 0, 0, 0);
            acc[1][1] = __builtin_amdgcn_mfma_f32_16x16x32_f16(afr1, wfr1, acc[1][1], 0, 0, 0);
        }
    }
    float rs_[2][4], rq_[2][4];
    if (STATS) {
#pragma unroll
        for (int ri = 0; ri < 2; ri++)
#pragma unroll
            for (int r = 0; r < 4; r++) { rs_[ri][r] = 0.f; rq_[ri][r] = 0.f; }
    }
#pragma unroll
    for (int ri = 0; ri < 2; ri++)
#pragma unroll
    for (int ci = 0; ci < 2; ci++) {
        const int lcol = wc * 32 + ci * 16 + fr;
        const int col = bn0 + lcol;
        const int row0 = bm0 + wr * 32 + ri * 16 + (l >> 4) * 4;
        if (isBC) {
            if (lcol < 32) {
                float* dst = (lcol < 16) ? bmo : cmo;
                const int cc = lcol & 15;
#pragma unroll
                for (int r = 0; r < 4; r++)
                    dst[(size_t)(row0 + r) * 16 + cc] = acc[ri][ci][r];
            }
        } else if (MODE == 2) {
            const float bv = bias[col];
            const int b = row0 >> 11, tl0 = row0 & 2047;
            if (col < 128) {
#pragma unroll
                for (int r = 0; r < 4; r++)
                    C[(size_t)(row0 + r) * 128 + col] = acc[ri][ci][r] + bv;
            } else if (col < 256) {
                const int hc = col - 128;
                short* kp = kbf + ((size_t)(b * 4 + (hc >> 5)) * 2048 + tl0) * 32 + (hc & 31);
#pragma unroll
                for (int r = 0; r < 4; r++)
                    kp[(size_t)r * 32] = f2bf(acc[ri][ci][r] + bv);
            } else {
                const int hc = col - 256;
                short4 vk;
#pragma unroll
                for (int r = 0; r < 4; r++)
                    ((short*)&vk)[r] = f2bf(acc[ri][ci][r] + bv);
                *(short4*)(vbf + ((size_t)(b * 4 + (hc >> 5)) * 32 + (hc & 31)) * 2048 + tl0) = vk;
            }
        } else {
            const float bv = BIAS ? bias[col] : 0.f;
#pragma unroll
            for (int r = 0; r < 4; r++) {
                float t = acc[ri][ci][r] + bv;
                if (ACT == 1) t = softplusf(t);
                if (ACT == 2) t = geluf(t);
                float* p = C + (size_t)(row0 + r) * ldc + col;
                if (ADD) t += *p;
                *p = t;
                if (STATS) { rs_[ri][r] += t; rq_[ri][r] += t * t; }
            }
        }
    }
    if (STATS) {
        const int g = l >> 4;
#pragma unroll
        for (int ri = 0; ri < 2; ri++)
#pragma unroll
        for (int r = 0; r < 4; r++) {
            float v = rs_[ri][r], q = rq_[ri][r];
            v += __shfl_xor(v, 1); q += __shfl_xor(q, 1);
            v += __shfl_xor(v, 2); q += __shfl_xor(q, 2);
            v += __shfl_xor(v, 4); q += __shfl_xor(q, 4);
            v += __shfl_xor(v, 8); q += __shfl_xor(q, 8);
            if (fr == 0) {
                int rowl = wr * 32 + ri * 16 + g * 4 + r;
                sRow[wc][rowl][0] = v;
                sRow[wc][rowl][1] = q;
            }
        }
        __syncthreads();
        if (tid < 128) {
            int row = tid >> 1, j = tid & 1;
            statsbuf[(size_t)(bm0 + row) * 4 + by * 2 + j] =
                sRow[0][row][j] + sRow[1][row][j];
        }
    }
}

// ---------------- causal depthwise conv (K=4) + silu, 4 channels/thread ----------------
__global__ __launch_bounds__(256) void conv_kernel(
    const float* __restrict__ xz, const float* __restrict__ cw,
    const float* __restrict__ cb, float* __restrict__ xc)
{
    int g = blockIdx.x * 256 + threadIdx.x;     // TOK * 64 threads
    int c4 = g & 63;
    int t  = (g >> 6) & 2047;
    int b  = g >> 17;
    int c  = c4 * 4;
    float4 w0 = *(const float4*)(cw + (size_t)c * 4);
    float4 w1 = *(const float4*)(cw + (size_t)(c + 1) * 4);
    float4 w2 = *(const float4*)(cw + (size_t)(c + 2) * 4);
    float4 w3 = *(const float4*)(cw + (size_t)(c + 3) * 4);
    float4 bi = *(const float4*)(cb + c);
    float4 xk[4];
#pragma unroll
    for (int kk = 0; kk < 4; kk++) {
        int tt = t - 3 + kk;
        if (tt >= 0) xk[kk] = *(const float4*)(xz + ((size_t)b * 2048 + tt) * 512 + c);
        else xk[kk] = make_float4(0.f, 0.f, 0.f, 0.f);
    }
    float4 r;
    r.x = bi.x + xk[0].x * w0.x + xk[1].x * w0.y + xk[2].x * w0.z + xk[3].x * w0.w;
    r.y = bi.y + xk[0].y * w1.x + xk[1].y * w1.y + xk[2].y * w1.z + xk[3].y * w1.w;
    r.z = bi.z + xk[0].z * w2.x + xk[1].z * w2.y + xk[2].z * w2.z + xk[3].z * w2.w;
    r.w = bi.w + xk[0].w * w3.x + xk[1].w * w3.y + xk[2].w * w3.z + xk[3].w * w3.w;
    r.x = siluf(r.x); r.y = siluf(r.y); r.z = siluf(r.z); r.w = siluf(r.w);
    *(float4*)(xc + ((size_t)b * 2048 + t) * 256 + c) = r;
}

// ---------------- scan phase 1 ----------------
__global__ __launch_bounds__(256) void scan1_kernel(
    const float* __restrict__ dt, const float* __restrict__ xc,
    const float* __restrict__ bm, const float* __restrict__ Alog,
    float* __restrict__ F, float* __restrict__ sumdt)
{
    int c = threadIdx.x;
    int k = blockIdx.x & (NC - 1);
    int b = blockIdx.x / NC;
    __shared__ float sB[CH][16];
    int t0 = k * CH;
    if (threadIdx.x < CH * 4) {
        int r = threadIdx.x >> 2, c4 = (threadIdx.x & 3) << 2;
        *(float4*)&sB[r][c4] = *(const float4*)(bm + ((size_t)b * 2048 + t0 + r) * 16 + c4);
    }
    float A2[16];
#pragma unroll
    for (int s = 0; s < 16; s++) A2[s] = -expf(Alog[(size_t)c * 16 + s]) * LOG2E;
    __syncthreads();
    float h[16] = {};
    float sd = 0.f;
    size_t base = ((size_t)b * 2048 + t0) * 256 + c;
    for (int tt = 0; tt < CH; tt++) {
        float d  = dt[base + (size_t)tt * 256];
        float xv = xc[base + (size_t)tt * 256];
        sd += d;
        float xdt = xv * d;
#pragma unroll
        for (int s = 0; s < 16; s++) h[s] = h[s] * EXP2F(A2[s] * d) + xdt * sB[tt][s];
    }
    size_t fo = (((size_t)b * NC + k) * 256 + c) * 16;
#pragma unroll
    for (int s = 0; s < 16; s += 4) *(float4*)(F + fo + s) = make_float4(h[s], h[s+1], h[s+2], h[s+3]);
    sumdt[((size_t)b * NC + k) * 256 + c] = sd;
}

// ---------------- scan phase 2: sequential chunk prefix, IN-PLACE on F ----------------
__global__ __launch_bounds__(256) void scan2_kernel(
    float* __restrict__ F, const float* __restrict__ sumdt,
    const float* __restrict__ Alog)
{
    int g = blockIdx.x * 256 + threadIdx.x;  // B*DI*DS = 16384
    int s = g & 15, c = (g >> 4) & 255, b = g >> 12;
    float A2 = -expf(Alog[(size_t)c * 16 + s]) * LOG2E;
    float h = 0.f;
    for (int k = 0; k < NC; k++) {
        size_t o = (((size_t)b * NC + k) * 256 + c) * 16 + s;
        float tmp = F[o];
        F[o] = h;
        h = h * EXP2F(A2 * sumdt[((size_t)b * NC + k) * 256 + c]) + tmp;
    }
}

// ---------------- scan phase 3 ----------------
__global__ __launch_bounds__(256) void scan3_kernel(
    const float* __restrict__ dt, const float* __restrict__ xc,
    const float* __restrict__ bm, const float* __restrict__ cm,
    const float* __restrict__ xz, const float* __restrict__ Alog,
    const float* __restrict__ Dp, const float* __restrict__ Hs,
    float* __restrict__ y)
{
    int c = threadIdx.x;
    int k = blockIdx.x & (NC - 1);
    int b = blockIdx.x / NC;
    __shared__ float sB[CH][16], sC[CH][16];
    int t0 = k * CH;
    if (threadIdx.x < CH * 4) {
        int r = threadIdx.x >> 2, c4 = (threadIdx.x & 3) << 2;
        *(float4*)&sB[r][c4] = *(const float4*)(bm + ((size_t)b * 2048 + t0 + r) * 16 + c4);
        *(float4*)&sC[r][c4] = *(const float4*)(cm + ((size_t)b * 2048 + t0 + r) * 16 + c4);
    }
    float A2[16];
#pragma unroll
    for (int s = 0; s < 16; s++) A2[s] = -expf(Alog[(size_t)c * 16 + s]) * LOG2E;
    __syncthreads();
    float h[16];
    size_t ho = (((size_t)b * NC + k) * 256 + c) * 16;
#pragma unroll
    for (int s = 0; s < 16; s++) h[s] = Hs[ho + s];
    float Dv = Dp[c];
    size_t base  = ((size_t)b * 2048 + t0) * 256 + c;
    size_t zbase = ((size_t)b * 2048 + t0) * 512 + 256 + c;
    for (int tt = 0; tt < CH; tt++) {
        float d  = dt[base + (size_t)tt * 256];
        float xv = xc[base + (size_t)tt * 256];
        float xdt = xv * d;
        float yv = 0.f;
#pragma unroll
        for (int s = 0; s < 16; s++) {
            h[s] = h[s] * EXP2F(A2[s] * d) + xdt * sB[tt][s];
            yv += h[s] * sC[tt][s];
        }
        yv += xv * Dv;
        float zv = xz[zbase + (size_t)tt * 512];
        y[base + (size_t)tt * 256] = yv * siluf(zv);
    }
}

// ---------------- bf16 MFMA flash attention, split-K x4, LDS-staged K/V ----------------
__global__ __launch_bounds__(256) void attn_part_kernel(
    const float* __restrict__ qbuf, const short* __restrict__ kbf,
    const short* __restrict__ vbf, float* __restrict__ pO, float* __restrict__ pml)
{
    __shared__ short Klds[2][64 * 32];
    __shared__ short Vlds[2][32 * 64];
    __shared__ short Pt[4][64][18];
    const int qt = blockIdx.x, b = blockIdx.z;
    const int h = blockIdx.y >> 2, sp = blockIdx.y & 3;
    const int tid = threadIdx.x;
    const int w = tid >> 6, l = tid & 63;
    const int q16 = l & 15, g = l >> 4;
    const float cQ = 0.25503634043f;      // log2(e)/sqrt(32)

    const int qrow = qt * 64 + w * 16 + q16;
    const float* qp = qbuf + ((size_t)(b * 2048 + qrow)) * 128 + 32 * h + g * 8;
    bf16x8 qfrag;
    {
        float qf[8];
        *(float4*)qf       = *(const float4*)qp;
        *(float4*)(qf + 4) = *(const float4*)(qp + 4);
#pragma unroll
        for (int i = 0; i < 8; i++) qfrag[i] = f2bf(qf[i] * cQ);
    }
    const int bh = b * 4 + h;
    const short* kb = kbf + ((size_t)bh * 2048) * 32;   // [k][d]
    const short* vb = vbf + ((size_t)bh * 32) * 2048;   // [d][k]

    const int vrow = tid >> 3;
    const int vsw  = ((tid & 7) * 16) ^ ((vrow & 7) << 4);
    const int ts0 = sp * 8;

    bf16x8 kst, vst;
    auto ldregs = [&](int t) {
        kst = *(const bf16x8*)(kb + (size_t)t * 2048 + tid * 8);
        vst = *(const bf16x8*)(vb + (size_t)vrow * 2048 + t * 64 + (vsw >> 1));
    };
    auto dswrite = [&](int buf) {
        *(bf16x8*)&Klds[buf][tid * 8] = kst;
        *(bf16x8*)&Vlds[buf][tid * 8] = vst;
    };

    float m = -1e30f, lsum = 0.f;
    f32x4 O0 = {0.f, 0.f, 0.f, 0.f}, O1 = {0.f, 0.f, 0.f, 0.f};
    const f32x4 zf = {0.f, 0.f, 0.f, 0.f};

    auto step = [&](int buf) {
        bf16x8 kf[4];
#pragma unroll
        for (int kt = 0; kt < 4; kt++)
            kf[kt] = *(const bf16x8*)&Klds[buf][(kt * 16 + q16) * 32 + g * 8];
        f32x4 St[4];
#pragma unroll
        for (int kt = 0; kt < 4; kt++)
            St[kt] = __builtin_amdgcn_mfma_f32_16x16x32_bf16(kf[kt], qfrag, zf, 0, 0, 0);
        float pm = St[0][0];
#pragma unroll
        for (int kt = 0; kt < 4; kt++)
#pragma unroll
            for (int r = 0; r < 4; r++) pm = fmaxf(pm, St[kt][r]);
        pm = fmaxf(pm, __shfl_xor(pm, 16));
        pm = fmaxf(pm, __shfl_xor(pm, 32));
        float mn = fmaxf(m, pm);
        float rs = EXP2F(m - mn);
        float ps = 0.f;
#pragma unroll
        for (int kt = 0; kt < 4; kt++)
#pragma unroll
            for (int r = 0; r < 4; r++) {
                float p = EXP2F(St[kt][r] - mn);
                ps += p;
                Pt[w][kt * 16 + g * 4 + r][q16] = f2bf(p);
            }
        ps += __shfl_xor(ps, 16);
        ps += __shfl_xor(ps, 32);
        lsum = lsum * rs + ps;
        m = mn;
        O0 *= rs; O1 *= rs;
#pragma unroll
        for (int c = 0; c < 2; c++) {
            bf16x8 pb;
#pragma unroll
            for (int i = 0; i < 8; i++) pb[i] = Pt[w][c * 32 + g * 8 + i][q16];
#pragma unroll
            for (int hf = 0; hf < 2; hf++) {
                const int d = q16 + 16 * hf;
                bf16x8 vf = *(const bf16x8*)&Vlds[buf][d * 64 + ((c * 32 + g * 8) ^ ((d & 7) << 3))];
                if (hf == 0) O0 = __builtin_amdgcn_mfma_f32_16x16x32_bf16(vf, pb, O0, 0, 0, 0);
                else         O1 = __builtin_amdgcn_mfma_f32_16x16x32_bf16(vf, pb, O1, 0, 0, 0);
            }
        }
    };

    ldregs(ts0);
    dswrite(0);
    ldregs(ts0 + 1);
    int cur = 0;
    for (int i = 0; i < 8; i++) {
        __syncthreads();
        if (i + 1 < 8) {
            dswrite(cur ^ 1);
            if (i + 2 < 8) ldregs(ts0 + i + 2);
        }
        step(cur);
        cur ^= 1;
    }

    size_t po = (((size_t)(bh * 4 + sp)) * 2048 + qrow) * 32;
#pragma unroll
    for (int r = 0; r < 4; r++) {
        pO[po + g * 4 + r]      = O0[r];
        pO[po + 16 + g * 4 + r] = O1[r];
    }
    if (g == 0) {
        size_t mo = (((size_t)(bh * 4 + sp)) * 2048 + qrow) * 2;
        pml[mo]     = m;
        pml[mo + 1] = lsum;
    }
}

// ---------------- attention combine: merge 4 split-K partials ----------------
__global__ __launch_bounds__(256) void attn_comb_kernel(
    const float* __restrict__ pO, const float* __restrict__ pml,
    float* __restrict__ aout)
{
    int gid = blockIdx.x * 256 + threadIdx.x;   // bh(4b) q(11b) d(5b)
    int d = gid & 31, q = (gid >> 5) & 2047, bh = gid >> 16;
    float m[4], lv[4], M = -1e30f;
#pragma unroll
    for (int s = 0; s < 4; s++) {
        size_t mo = (((size_t)(bh * 4 + s)) * 2048 + q) * 2;
        m[s] = pml[mo]; lv[s] = pml[mo + 1];
        M = fmaxf(M, m[s]);
    }
    float L = 0.f, o = 0.f;
#pragma unroll
    for (int s = 0; s < 4; s++) {
        float wgt = EXP2F(m[s] - M);
        L += lv[s] * wgt;
        o += pO[(((size_t)(bh * 4 + s)) * 2048 + q) * 32 + d] * wgt;
    }
    int b = bh >> 2, h = bh & 3;
    aout[((size_t)(b * 2048 + q)) * 128 + h * 32 + d] = o / L;
}

// ---------------- head ----------------
__global__ __launch_bounds__(128) void head_kernel(
    const float* __restrict__ x, const float* __restrict__ w,
    const float* __restrict__ bsp, const float* __restrict__ hw,
    const float* __restrict__ hb, float* __restrict__ out)
{
    int bb = blockIdx.x;
    int d = threadIdx.x;
    int wid = d >> 6, lane = d & 63;
    float v = x[(size_t)bb * 2048 * 128 + d];
    float s = v, sq = v * v;
#pragma unroll
    for (int o = 32; o > 0; o >>= 1) { s += __shfl_xor(s, o); sq += __shfl_xor(sq, o); }
    __shared__ float red[4];
    if (lane == 0) { red[wid] = s; red[2 + wid] = sq; }
    __syncthreads();
    s = red[0] + red[1]; sq = red[2] + red[3];
    float mu = s * (1.f / 128.f);
    float var = sq * (1.f / 128.f) - mu * mu;
    float xn = (v - mu) * rsqrtf(var + 1e-5f) * w[d] + bsp[d];
    float pr = xn * hw[d];
#pragma unroll
    for (int o = 32; o > 0; o >>= 1) pr += __shfl_xor(pr, o);
    __syncthreads();
    if (lane == 0) red[wid] = pr;
    __syncthreads();
    if (d == 0) out[bb] = red[0] + red[1] + hb[0];
}

// ---------------- workspace layout (floats) ----------------
constexpr size_t OFF_X  = 0;                          // x: 1M
constexpr size_t OFF_XZ = (size_t)1 << 20;            // xz / ff / attn pO: 4M
constexpr size_t OFF_XC = (size_t)5 << 20;            // xc (mamba) / qbuf (attn): 2M
constexpr size_t OFF_DT = (size_t)7 << 20;            // dt / attn pml: 2M
constexpr size_t OFF_Y  = (size_t)9 << 20;            // y / attn out: 2M
constexpr size_t OFF_BM = (size_t)11 << 20;           // 128K
constexpr size_t OFF_CM = OFF_BM + 131072;            // 128K
constexpr size_t OFF_SD = OFF_CM + 131072;            // 128K
constexpr size_t OFF_ST = OFF_SD + 131072;            // 32K (TOK x 4 partial stats)
constexpr size_t OFF_F  = OFF_ST + 32768;             // 2M: scan F / attn kbf+vbf / embed enc
constexpr size_t OFF_WF = OFF_F + ((size_t)2 << 20);  // 720896 floats of f16 weights
constexpr size_t WS_FLOATS = OFF_WF + 720896;

extern "C" void kernel_launch(void* const* d_in, const int* in_sizes, int n_in,
                              void* d_out, int out_size, void* d_ws, size_t ws_size,
                              hipStream_t stream)
{
    const int*   ids   = (const int*)d_in[0];
    const int*   tts   = (const int*)d_in[1];
    const float* tstmp = (const float*)d_in[2];
    const float* emb   = (const float*)d_in[3];
    const float* temb  = (const float*)d_in[4];
    const float* tef   = (const float*)d_in[5];
    const float* tep   = (const float*)d_in[6];
    const float* tew   = (const float*)d_in[7];
    const float* tebi  = (const float*)d_in[8];
    const float* mnw   = (const float*)d_in[9];
    const float* mnb   = (const float*)d_in[10];
    const float* minw  = (const float*)d_in[11];
    const float* mcwp  = (const float*)d_in[12];
    const float* mcb   = (const float*)d_in[13];
    const float* mdtw  = (const float*)d_in[14];
    const float* mdtb  = (const float*)d_in[15];
    const float* mbw   = (const float*)d_in[16];
    const float* mcw2  = (const float*)d_in[17];
    const float* mD    = (const float*)d_in[18];
    const float* mAl   = (const float*)d_in[19];
    const float* mow   = (const float*)d_in[20];
    const float* al1w  = (const float*)d_in[21];
    const float* al1b  = (const float*)d_in[22];
    const float* aqkvw = (const float*)d_in[23];
    const float* aqkvb = (const float*)d_in[24];
    const float* aow   = (const float*)d_in[25];
    const float* aob   = (const float*)d_in[26];
    const float* al2w  = (const float*)d_in[27];
    const float* al2b  = (const float*)d_in[28];
    const float* af1w  = (const float*)d_in[29];
    const float* af1b  = (const float*)d_in[30];
    const float* af2w  = (const float*)d_in[31];
    const float* af2b  = (const float*)d_in[32];
    const float* hlnw  = (const float*)d_in[33];
    const float* hlnb  = (const float*)d_in[34];
    const float* hw    = (const float*)d_in[35];
    const float* hb    = (const float*)d_in[36];
    float* out = (float*)d_out;
    float* wsf = (float*)d_ws;
    if (ws_size < WS_FLOATS * sizeof(float)) return;

    float* x    = wsf + OFF_X;
    float* xz   = wsf + OFF_XZ;
    float* xc   = wsf + OFF_XC;
    float* dtb  = wsf + OFF_DT;
    float* yb   = wsf + OFF_Y;
    float* bm   = wsf + OFF_BM;
    float* cm   = wsf + OFF_CM;
    float* sdb  = wsf + OFF_SD;
    float* stats4 = wsf + OFF_ST;                  // [TOK][4] partial LN stats
    float* Fb   = wsf + OFF_F;
    float* ff   = xz;
    float* aout = yb;
    float* qbuf = xc;                              // attn-time only
    float* pO   = xz;                              // attn-time only
    float* pml  = dtb;                             // attn-time only
    float* encb = Fb;                              // embed-time only
    short* kbf  = (short*)(wsf + OFF_F);           // attn-time only
    short* vbf  = (short*)(wsf + OFF_F + ((size_t)1 << 20));
    _Float16* wf16 = (_Float16*)(wsf + OFF_WF);

    const _Float16* tew16   = wf16;
    const _Float16* minw16  = wf16 + 16384;
    const _Float16* mdtw16  = wf16 + 409600;
    const _Float16* mbw16   = wf16 + 802816;
    const _Float16* mcw216  = wf16 + 827392;
    const _Float16* mow16   = wf16 + 851968;
    const _Float16* aqkvw16 = wf16 + 1048576;
    const _Float16* aow16   = wf16 + 1146880;
    const _Float16* af1w16  = wf16 + 1179648;
    const _Float16* af2w16  = wf16 + 1310720;

    wprep_kernel<<<dim3(1536, 10), 256, 0, stream>>>(
        tew, minw, mdtw, mbw, mcw2, mow, aqkvw, aow, af1w, af2w, wf16);

    gather_enc_kernel<<<TOK / 2, 256, 0, stream>>>(ids, tts, tstmp, emb, temb, tef, tep, x, encb);
    // embed GEMM produces x AND its LN partial stats
    gemm64_kernel<0, true, true, false, 0, true><<<dim3(128, 2), 256, 0, stream>>>(
        encb, tew16, tebi, x, nullptr, nullptr, stats4, nullptr, nullptr,
        nullptr, nullptr, nullptr, nullptr, TOK, 128, 128, 128, 128);

    int mi = 0, ai = 0;
    for (int i = 0; i < 8; i++) {
        if ((i + 1) % 4 == 0) {
            // -------- attention layer --------
            gemm64_kernel<0, true, false, true, 2, false><<<dim3(128, 6), 256, 0, stream>>>(
                x, aqkvw16 + (size_t)ai * 49152, aqkvb + ai * 384, qbuf,
                al1w + ai * 128, al1b + ai * 128, stats4, nullptr, nullptr,
                nullptr, nullptr, kbf, vbf, TOK, 384, 128, 128, 128);
            attn_part_kernel<<<dim3(32, 16, Bb), 256, 0, stream>>>(qbuf, kbf, vbf, pO, pml);
            attn_comb_kernel<<<4096, 256, 0, stream>>>(pO, pml, aout);
            gemm64_kernel<0, true, true, false, 0, true><<<dim3(128, 2), 256, 0, stream>>>(
                aout, aow16 + (size_t)ai * 16384, aob + ai * 128, x,
                nullptr, nullptr, stats4, nullptr, nullptr,
                nullptr, nullptr, nullptr, nullptr, TOK, 128, 128, 128, 128);
            gemm64_kernel<2, true, false, true, 0, false><<<dim3(128, 8), 256, 0, stream>>>(
                x, af1w16 + (size_t)ai * 65536, af1b + ai * 512, ff,
                al2w + ai * 128, al2b + ai * 128, stats4, nullptr, nullptr,
                nullptr, nullptr, nullptr, nullptr, TOK, 512, 128, 128, 512);
            gemm64_kernel<0, true, true, false, 0, true><<<dim3(128, 2), 256, 0, stream>>>(
                ff, af2w16 + (size_t)ai * 65536, af2b + ai * 128, x,
                nullptr, nullptr, stats4, nullptr, nullptr,
                nullptr, nullptr, nullptr, nullptr, TOK, 128, 512, 512, 128);
            ai++;
        } else {
            // -------- mamba layer --------
            const float* Al = mAl + (size_t)mi * DIi * 16;
            gemm64_kernel<0, false, false, true, 0, false><<<dim3(128, 8), 256, 0, stream>>>(
                x, minw16 + (size_t)mi * 65536, nullptr, xz,
                mnw + mi * 128, mnb + mi * 128, stats4, nullptr, nullptr,
                nullptr, nullptr, nullptr, nullptr, TOK, 512, 128, 128, 512);
            conv_kernel<<<2048, 256, 0, stream>>>(xz, mcwp + (size_t)mi * DIi * 4, mcb + mi * DIi, xc);
            gemm64_kernel<1, true, false, false, 1, false><<<dim3(128, 5), 256, 0, stream>>>(
                xc, mdtw16 + (size_t)mi * 65536, mdtb + mi * 256, dtb,
                nullptr, nullptr, nullptr,
                mbw16 + (size_t)mi * 4096, mcw216 + (size_t)mi * 4096,
                bm, cm, nullptr, nullptr, TOK, 256, 256, 256, 256);
            scan1_kernel<<<Bb * NC, 256, 0, stream>>>(dtb, xc, bm, Al, Fb, sdb);
            scan2_kernel<<<64, 256, 0, stream>>>(Fb, sdb, Al);
            scan3_kernel<<<Bb * NC, 256, 0, stream>>>(dtb, xc, bm, cm, xz, Al, mD + mi * 256, Fb, yb);
            gemm64_kernel<0, false, true, false, 0, true><<<dim3(128, 2), 256, 0, stream>>>(
                yb, mow16 + (size_t)mi * 32768, nullptr, x,
                nullptr, nullptr, stats4, nullptr, nullptr,
                nullptr, nullptr, nullptr, nullptr, TOK, 128, 256, 256, 128);
            mi++;
        }
    }
    head_kernel<<<Bb, 128, 0, stream>>>(x, hlnw, hlnb, hw, hb, out);
}